// Round 6
// baseline (1253.470 us; speedup 1.0000x reference)
//
#include <hip/hip_runtime.h>

// Shapes: B=4, S=2048, D=256, H=8, KD=256; N=B*S=8192; H*KD=2048.
using bf16x8 = __attribute__((ext_vector_type(8))) __bf16;
using f32x4  = __attribute__((ext_vector_type(4))) float;
using f32x16 = __attribute__((ext_vector_type(16))) float;
typedef unsigned short u16;
typedef const __attribute__((address_space(1))) void* gas_p;
typedef __attribute__((address_space(3))) void* las_p;

#define LOG2E 1.4426950408889634f

__device__ __forceinline__ u16 f2bf(float f) {
  union { float f; unsigned u; } v; v.f = f;
  unsigned r = v.u + 0x7fffu + ((v.u >> 16) & 1u);
  return (u16)(r >> 16);
}

__device__ __forceinline__ unsigned pkbf(float a, float b) {
  unsigned r;
  asm("v_cvt_pk_bf16_f32 %0, %1, %2" : "=v"(r) : "v"(a), "v"(b));
  return r;
}

// 2^x via the native transcendental unit (one v_exp_f32).
__device__ __forceinline__ float exp2v(float x) {
  float r;
  asm("v_exp_f32 %0, %1" : "=v"(r) : "v"(x));
  return r;
}

__device__ __forceinline__ void gload16(const void* g, void* l) {
  __builtin_amdgcn_global_load_lds((gas_p)g, (las_p)l, 16, 0, 0);
}

#define MFMA(a, b, c)   __builtin_amdgcn_mfma_f32_16x16x32_bf16((a), (b), (c), 0, 0, 0)
#define MFMA32(a, b, c) __builtin_amdgcn_mfma_f32_32x32x16_bf16((a), (b), (c), 0, 0, 0)

// ---------------------------------------------------------------------------
// Kernel 1: transpose + f32->bf16 convert for the 4 weight matrices.
__global__ __launch_bounds__(256) void transpose_conv(
    const float* __restrict__ Wq, const float* __restrict__ Wk,
    const float* __restrict__ Wv, const float* __restrict__ Wo,
    u16* __restrict__ wqt, u16* __restrict__ wkt,
    u16* __restrict__ wvt, u16* __restrict__ wot)
{
  int z = blockIdx.y;
  const float* src = (z == 0) ? Wq : (z == 1) ? Wk : (z == 2) ? Wv : Wo;
  u16* dst = (z == 0) ? wqt : (z == 1) ? wkt : (z == 2) ? wvt : wot;
  int C = (z < 3) ? 2048 : 256;   // src cols
  int R = (z < 3) ? 256 : 2048;   // src rows
  int TC = C >> 5;
  int tc = blockIdx.x % TC, tr = blockIdx.x / TC;
  __shared__ float tile[32][33];
  int j = threadIdx.x & 31, i0 = threadIdx.x >> 5;
#pragma unroll
  for (int p = 0; p < 4; p++)
    tile[i0 + p * 8][j] = src[(tr * 32 + i0 + p * 8) * C + tc * 32 + j];
  __syncthreads();
#pragma unroll
  for (int p = 0; p < 4; p++)
    dst[(tc * 32 + i0 + p * 8) * R + tr * 32 + j] = f2bf(tile[j][i0 + p * 8]);
}

// ---------------------------------------------------------------------------
// Kernel 2: LayerNorm for the 3 input streams, f32 -> bf16. One wave per row.
__global__ __launch_bounds__(256) void ln3_kernel(
    const float* __restrict__ xq, const float* __restrict__ xk, const float* __restrict__ xv,
    const float* __restrict__ gq, const float* __restrict__ bq,
    const float* __restrict__ gk, const float* __restrict__ bk,
    const float* __restrict__ gv, const float* __restrict__ bv,
    u16* __restrict__ oq, u16* __restrict__ ok, u16* __restrict__ ov)
{
  int z = blockIdx.y;
  const float* x = (z == 0) ? xq : (z == 1) ? xk : xv;
  const float* g = (z == 0) ? gq : (z == 1) ? gk : gv;
  const float* be = (z == 0) ? bq : (z == 1) ? bk : bv;
  u16* o = (z == 0) ? oq : (z == 1) ? ok : ov;
  int w = threadIdx.x >> 6, l = threadIdx.x & 63;
  int row = blockIdx.x * 4 + w;
  float4 x4 = *(const float4*)(x + row * 256 + l * 4);
  float s = x4.x + x4.y + x4.z + x4.w;
  float sq = x4.x * x4.x + x4.y * x4.y + x4.z * x4.z + x4.w * x4.w;
#pragma unroll
  for (int mm = 1; mm < 64; mm <<= 1) { s += __shfl_xor(s, mm); sq += __shfl_xor(sq, mm); }
  float mu = s * (1.f / 256.f);
  float var = sq * (1.f / 256.f) - mu * mu;
  float rs = rsqrtf(var + 1e-5f);
  float4 g4 = *(const float4*)(g + l * 4);
  float4 b4 = *(const float4*)(be + l * 4);
  ushort4 o4;
  o4.x = f2bf((x4.x - mu) * rs * g4.x + b4.x);
  o4.y = f2bf((x4.y - mu) * rs * g4.y + b4.y);
  o4.z = f2bf((x4.z - mu) * rs * g4.z + b4.z);
  o4.w = f2bf((x4.w - mu) * rs * g4.w + b4.w);
  *(ushort4*)(o + row * 256 + l * 4) = o4;
}

// ---------------------------------------------------------------------------
// Kernel 3: projection GEMM. C[8192][2048] = A[8192][256] * W[256][2048] (+bias)
// z==2 (V stream) writes V^T [32 bh][256 kd][2048 s] directly (fused transpose).
// q stream pre-scaled by (1/16)*log2(e) so attention softmax runs in exp2 domain.
__global__ __launch_bounds__(256) void proj_gemm(
    const u16* __restrict__ qn, const u16* __restrict__ kn, const u16* __restrict__ vn,
    const u16* __restrict__ wqt, const u16* __restrict__ wkt, const u16* __restrict__ wvt,
    const float* __restrict__ bq, const float* __restrict__ bk, const float* __restrict__ bv,
    u16* __restrict__ qo, u16* __restrict__ ko, u16* __restrict__ vo)
{
  __shared__ u16 As[128 * 64];
  __shared__ u16 Bs[128 * 64];
  int z = blockIdx.z;
  const u16* A  = (z == 0) ? qn : (z == 1) ? kn : vn;
  const u16* Bt = (z == 0) ? wqt : (z == 1) ? wkt : wvt;
  const float* bias = (z == 0) ? bq : (z == 1) ? bk : bv;
  u16* Co = (z == 0) ? qo : (z == 1) ? ko : vo;
  float scale = (z == 0) ? 0.0625f * LOG2E : 1.0f;

  int i0 = blockIdx.x * 128, n0 = blockIdx.y * 128;
  int tid = threadIdx.x, w = tid >> 6, l = tid & 63;
  int wr = w >> 1, wc = w & 1, l15 = l & 15, qv = l >> 4;

  f32x4 acc[4][4] = {};

  for (int k0 = 0; k0 < 256; k0 += 64) {
    __syncthreads();
#pragma unroll
    for (int j = 0; j < 4; j++) {
      int c = (w * 4 + j) * 64 + l;
      int row = c >> 3, co = (c & 7) * 8;
      gload16(A + (i0 + row) * 256 + k0 + co, (char*)As + (w * 4 + j) * 1024);
      gload16(Bt + (n0 + row) * 256 + k0 + co, (char*)Bs + (w * 4 + j) * 1024);
    }
    __syncthreads();
#pragma unroll
    for (int kk = 0; kk < 2; kk++) {
      bf16x8 a[4], bfr[4];
#pragma unroll
      for (int m = 0; m < 4; m++)
        a[m] = *(const bf16x8*)(As + (wr * 64 + m * 16 + l15) * 64 + kk * 32 + qv * 8);
#pragma unroll
      for (int n = 0; n < 4; n++)
        bfr[n] = *(const bf16x8*)(Bs + (wc * 64 + n * 16 + l15) * 64 + kk * 32 + qv * 8);
#pragma unroll
      for (int m = 0; m < 4; m++)
#pragma unroll
        for (int n = 0; n < 4; n++) acc[m][n] = MFMA(a[m], bfr[n], acc[m][n]);
    }
  }

  if (z == 2) {
    // V^T epilogue: vt[(bb*8+h)*256 + kd][ss..ss+3], 8B packed stores.
#pragma unroll
    for (int n = 0; n < 4; n++) {
      int col = n0 + wc * 64 + n * 16 + l15;
      float bc = bias[col];
      int h = col >> 8, kd = col & 255;
#pragma unroll
      for (int m = 0; m < 4; m++) {
        int row0 = i0 + wr * 64 + m * 16 + qv * 4;
        int bb = row0 >> 11, ss = row0 & 2047;
        ushort4 o4;
        o4.x = f2bf(acc[m][n][0] + bc);
        o4.y = f2bf(acc[m][n][1] + bc);
        o4.z = f2bf(acc[m][n][2] + bc);
        o4.w = f2bf(acc[m][n][3] + bc);
        *(ushort4*)(Co + ((size_t)(bb * 8 + h) * 256 + kd) * 2048 + ss) = o4;
      }
    }
  } else {
#pragma unroll
    for (int n = 0; n < 4; n++) {
      int col = n0 + wc * 64 + n * 16 + l15;
      float bc = bias[col];
      int h = col >> 8, kd = col & 255;
#pragma unroll
      for (int m = 0; m < 4; m++) {
#pragma unroll
        for (int r = 0; r < 4; r++) {
          int row = i0 + wr * 64 + m * 16 + qv * 4 + r;
          int bb = row >> 11, ss = row & 2047;
          Co[((bb * 8 + h) * 2048 + ss) * 256 + kd] = f2bf((acc[m][n][r] + bc) * scale);
        }
      }
    }
  }
}

// ---------------------------------------------------------------------------
// Kernel 5: flash attention, 32x32x16 MFMA, swapped operands.
// 4 waves x 64 q (two 32-q blocks per wave) = 256 q/block; KVBLK=64.
// Each K/V LDS frag read feeds TWO MFMAs (one per q-block) -> LDS traffic
// halves vs the 8-wave/32-q version. Double-buffered 2x64KB LDS, 1 block/CU,
// 1 wave/SIMD, ~470 VGPR (launch_bounds(256,1)).
// Softmax in exp2 domain (Q pre-scaled by log2e/16); exp2 via v_exp_f32.
// Grid 256 flat; XCD swizzle keeps one bh's 8 q-blocks on one XCD.
__global__ __launch_bounds__(256, 1) void flash_attn(
    const u16* __restrict__ q, const u16* __restrict__ k,
    const u16* __restrict__ vt, u16* __restrict__ o)
{
  __shared__ char lds[131072];
  int f = blockIdx.x;
  int idx = f >> 3;
  int bh = (f & 7) * 4 + (idx & 3);
  int qt = idx >> 2;
  int b = bh >> 3, hh = bh & 7;
  int tid = threadIdx.x, w = tid >> 6, l = tid & 63;
  int l31 = l & 31, h = l >> 5;

  const u16* Q = q + (size_t)(bh * 2048 + qt * 256 + w * 64) * 256;
  const u16* K = k + (size_t)bh * 2048 * 256;
  const u16* V = vt + (size_t)bh * 256 * 2048;   // V^T [256][2048]

  // Q B-fragments for the two q-blocks: lane q-row = l31 (+32 for block 1).
  bf16x8 qf0[16], qf1[16];
#pragma unroll
  for (int dt = 0; dt < 16; dt++) {
    qf0[dt] = *(const bf16x8*)(Q + l31 * 256 + dt * 16 + h * 8);
    qf1[dt] = *(const bf16x8*)(Q + (32 + l31) * 256 + dt * 16 + h * 8);
  }

  f32x16 oacc0[8] = {}, oacc1[8] = {};
  float m0 = -1e30f, m1 = -1e30f, ls0 = 0.f, ls1 = 0.f;

  // Stage K/V tile t (64 s) into base: K 32KB [64 rows x 512B, granule^row],
  // V 32KB [128 rows x 256B, granule^(row&15)]. 4 waves x 16 gload16.
  auto stage = [&](int t, char* base) {
#pragma unroll
    for (int j = 0; j < 8; j++) {
      int c = w * 8 + j;
      int off = c * 1024 + l * 16;
      {
        int r = off >> 9, ps = (off >> 4) & 31;
        gload16(K + (size_t)(t * 64 + r) * 256 + ((ps ^ (r & 31)) << 3), base + off);
      }
      {
        int r = off >> 8, g = (off >> 4) & 15;
        int gg = g ^ (r & 15);
        int d = r * 2 + (gg >> 3), s0 = (gg & 7) * 8;
        gload16(V + (size_t)d * 2048 + t * 64 + s0, base + 32768 + off);
      }
    }
  };

  stage(0, lds);
  __syncthreads();

  for (int t = 0; t < 32; t++) {
    char* cur = lds + (size_t)(t & 1) * 65536;
    char* nxt = lds + (size_t)((t + 1) & 1) * 65536;
    if (t + 1 < 32) stage(t + 1, nxt);   // async DMA into other buffer

    unsigned pw0[16], pw1[16];
    // ---- two s-halves of 32; each K frag feeds both q-blocks.
#pragma unroll
    for (int sh = 0; sh < 2; sh++) {
      const char* kb = cur + sh * 16384;
      f32x16 pA = {}, pB = {};
      __builtin_amdgcn_s_setprio(1);
#pragma unroll
      for (int dt = 0; dt < 16; dt++) {
        bf16x8 kf = *(const bf16x8*)(kb + l31 * 512 + (((dt * 2 + h) ^ l31) << 4));
        pA = MFMA32(kf, qf0[dt], pA);
        pB = MFMA32(kf, qf1[dt], pB);
      }
      __builtin_amdgcn_s_setprio(0);

      // ---- online softmax, block 0 (lane-local q = l31).
      {
        float n0 = fmaxf(fmaxf(pA[0], pA[1]), fmaxf(pA[2], pA[3]));
        float n1 = fmaxf(fmaxf(pA[4], pA[5]), fmaxf(pA[6], pA[7]));
        float n2 = fmaxf(fmaxf(pA[8], pA[9]), fmaxf(pA[10], pA[11]));
        float n3 = fmaxf(fmaxf(pA[12], pA[13]), fmaxf(pA[14], pA[15]));
        float mt = fmaxf(fmaxf(n0, n1), fmaxf(n2, n3));
        mt = fmaxf(mt, __shfl_xor(mt, 32));
        if (__any(mt > m0 + 8.0f * LOG2E)) {      // defer-max (T13)
          float mn = fmaxf(m0, mt);
          float fsc = exp2v(m0 - mn);
          ls0 *= fsc;
#pragma unroll
          for (int dt = 0; dt < 8; dt++)
#pragma unroll
            for (int i = 0; i < 16; i++) oacc0[dt][i] *= fsc;
          m0 = mn;
        }
#pragma unroll
        for (int i = 0; i < 16; i++) { pA[i] = exp2v(pA[i] - m0); ls0 += pA[i]; }
#pragma unroll
        for (int i = 0; i < 8; i++) pw0[sh * 8 + i] = pkbf(pA[2 * i], pA[2 * i + 1]);
      }
      // ---- online softmax, block 1.
      {
        float n0 = fmaxf(fmaxf(pB[0], pB[1]), fmaxf(pB[2], pB[3]));
        float n1 = fmaxf(fmaxf(pB[4], pB[5]), fmaxf(pB[6], pB[7]));
        float n2 = fmaxf(fmaxf(pB[8], pB[9]), fmaxf(pB[10], pB[11]));
        float n3 = fmaxf(fmaxf(pB[12], pB[13]), fmaxf(pB[14], pB[15]));
        float mt = fmaxf(fmaxf(n0, n1), fmaxf(n2, n3));
        mt = fmaxf(mt, __shfl_xor(mt, 32));
        if (__any(mt > m1 + 8.0f * LOG2E)) {
          float mn = fmaxf(m1, mt);
          float fsc = exp2v(m1 - mn);
          ls1 *= fsc;
#pragma unroll
          for (int dt = 0; dt < 8; dt++)
#pragma unroll
            for (int i = 0; i < 16; i++) oacc1[dt][i] *= fsc;
          m1 = mn;
        }
#pragma unroll
        for (int i = 0; i < 16; i++) { pB[i] = exp2v(pB[i] - m1); ls1 += pB[i]; }
#pragma unroll
        for (int i = 0; i < 8; i++) pw1[sh * 8 + i] = pkbf(pB[2 * i], pB[2 * i + 1]);
      }
    }

    // ---- PV: per k-step build P^T B-frags; each V frag feeds both q-blocks.
#pragma unroll
    for (int kt = 0; kt < 4; kt++) {
      unsigned a0 = __shfl_xor(pw0[4 * kt + 0], 32);
      unsigned a1 = __shfl_xor(pw0[4 * kt + 1], 32);
      unsigned a2 = __shfl_xor(pw0[4 * kt + 2], 32);
      unsigned a3 = __shfl_xor(pw0[4 * kt + 3], 32);
      union { unsigned u[4]; bf16x8 v; } pa;
      pa.u[0] = h ? a2 : pw0[4 * kt + 0];
      pa.u[1] = h ? a3 : pw0[4 * kt + 1];
      pa.u[2] = h ? pw0[4 * kt + 2] : a0;
      pa.u[3] = h ? pw0[4 * kt + 3] : a1;
      unsigned b0 = __shfl_xor(pw1[4 * kt + 0], 32);
      unsigned b1 = __shfl_xor(pw1[4 * kt + 1], 32);
      unsigned b2 = __shfl_xor(pw1[4 * kt + 2], 32);
      unsigned b3 = __shfl_xor(pw1[4 * kt + 3], 32);
      union { unsigned u[4]; bf16x8 v; } pb;
      pb.u[0] = h ? b2 : pw1[4 * kt + 0];
      pb.u[1] = h ? b3 : pw1[4 * kt + 1];
      pb.u[2] = h ? pw1[4 * kt + 2] : b0;
      pb.u[3] = h ? pw1[4 * kt + 3] : b1;
      __builtin_amdgcn_s_setprio(1);
#pragma unroll
      for (int dt = 0; dt < 8; dt++) {
        int d = dt * 32 + l31;
        int r = d >> 1;
        int lsl = (d & 1) * 8 + kt * 2 + h;
        bf16x8 vf = *(const bf16x8*)(cur + 32768 + r * 256 + ((lsl ^ (r & 15)) << 4));
        oacc0[dt] = MFMA32(vf, pa.v, oacc0[dt]);
        oacc1[dt] = MFMA32(vf, pb.v, oacc1[dt]);
      }
      __builtin_amdgcn_s_setprio(0);
    }

    asm volatile("s_waitcnt vmcnt(0)" ::: "memory");
    __syncthreads();
  }

  // ---- epilogue: normalize (lane-local q), transpose via LDS, store 16B.
  __syncthreads();
  char* wbase = (char*)lds + w * 8192;   // 16 q-rows x 512B per wave region
  int qr15 = l31 & 15;

  auto epi = [&](const f32x16 (&oa)[8], float ls, int jq) {
    float inv = 1.0f / (ls + __shfl_xor(ls, 32));
#pragma unroll
    for (int ph = 0; ph < 2; ph++) {
      if ((l31 >> 4) == ph) {
#pragma unroll
        for (int dt = 0; dt < 8; dt++) {
#pragma unroll
          for (int rg = 0; rg < 4; rg++) {
            uint2 uu;
            uu.x = pkbf(oa[dt][rg * 4 + 0] * inv, oa[dt][rg * 4 + 1] * inv);
            uu.y = pkbf(oa[dt][rg * 4 + 2] * inv, oa[dt][rg * 4 + 3] * inv);
            *(uint2*)(wbase + qr15 * 512 + ((dt * 64 + rg * 16) ^ (qr15 << 4)) + h * 8) = uu;
          }
        }
      }
      asm volatile("s_waitcnt lgkmcnt(0)" ::: "memory");
      __builtin_amdgcn_sched_barrier(0);
#pragma unroll
      for (int c = 0; c < 8; c++) {
        int qr = c * 2 + h;
        uint4 vv = *(const uint4*)(wbase + qr * 512 + ((l31 ^ qr) << 4));
        int s = qt * 256 + w * 64 + jq * 32 + ph * 16 + qr;
        *(uint4*)((char*)o + (size_t)(b * 2048 + s) * 4096 + hh * 512 + l31 * 16) = vv;
      }
      asm volatile("s_waitcnt lgkmcnt(0)" ::: "memory");
    }
  };
  epi(oacc0, ls0, 0);
  epi(oacc1, ls1, 1);
}

// ---------------------------------------------------------------------------
// Kernel 6: output projection + bias + residual.
__global__ __launch_bounds__(256) void out_gemm(
    const u16* __restrict__ A, const u16* __restrict__ Bt,
    const float* __restrict__ bo, const float* __restrict__ resid,
    float* __restrict__ out)
{
  __shared__ u16 As[128 * 64];
  __shared__ u16 Bs[64 * 64];
  int i0 = blockIdx.x * 128, n0 = blockIdx.y * 64;
  int tid = threadIdx.x, w = tid >> 6, l = tid & 63, l15 = l & 15, qv = l >> 4;

  f32x4 acc[2][4] = {};

  for (int k0 = 0; k0 < 2048; k0 += 64) {
    __syncthreads();
#pragma unroll
    for (int j = 0; j < 4; j++) {
      int c = (w * 4 + j) * 64 + l;
      int row = c >> 3, co = (c & 7) * 8;
      gload16(A + (i0 + row) * 2048 + k0 + co, (char*)As + (w * 4 + j) * 1024);
    }
#pragma unroll
    for (int j = 0; j < 2; j++) {
      int c = (w * 2 + j) * 64 + l;
      int row = c >> 3, co = (c & 7) * 8;
      gload16(Bt + (n0 + row) * 2048 + k0 + co, (char*)Bs + (w * 2 + j) * 1024);
    }
    __syncthreads();
#pragma unroll
    for (int kk = 0; kk < 2; kk++) {
      bf16x8 a[2], bfr[4];
#pragma unroll
      for (int m = 0; m < 2; m++)
        a[m] = *(const bf16x8*)(As + (w * 32 + m * 16 + l15) * 64 + kk * 32 + qv * 8);
#pragma unroll
      for (int n = 0; n < 4; n++)
        bfr[n] = *(const bf16x8*)(Bs + (n * 16 + l15) * 64 + kk * 32 + qv * 8);
#pragma unroll
      for (int m = 0; m < 2; m++)
#pragma unroll
        for (int n = 0; n < 4; n++) acc[m][n] = MFMA(a[m], bfr[n], acc[m][n]);
    }
  }

#pragma unroll
  for (int n = 0; n < 4; n++) {
    int col = n0 + n * 16 + l15;
    float bc = bo[col];
#pragma unroll
    for (int m = 0; m < 2; m++)
#pragma unroll
      for (int r = 0; r < 4; r++) {
        int row = i0 + w * 32 + m * 16 + qv * 4 + r;
        out[row * 256 + col] = acc[m][n][r] + bc + resid[row * 256 + col];
      }
  }
}

// ---------------------------------------------------------------------------
extern "C" void kernel_launch(void* const* d_in, const int* in_sizes, int n_in,
                              void* d_out, int out_size, void* d_ws, size_t ws_size,
                              hipStream_t stream)
{
  const float* inq  = (const float*)d_in[0];
  const float* key  = (const float*)d_in[1];
  const float* val  = (const float*)d_in[2];
  const float* gq   = (const float*)d_in[3];
  const float* bqln = (const float*)d_in[4];
  const float* gk   = (const float*)d_in[5];
  const float* bkln = (const float*)d_in[6];
  const float* gv   = (const float*)d_in[7];
  const float* bvln = (const float*)d_in[8];
  const float* Wq   = (const float*)d_in[9];
  const float* bq   = (const float*)d_in[10];
  const float* Wk   = (const float*)d_in[11];
  const float* bk   = (const float*)d_in[12];
  const float* Wv   = (const float*)d_in[13];
  const float* bv   = (const float*)d_in[14];
  const float* Wo   = (const float*)d_in[15];
  const float* bo   = (const float*)d_in[16];

  char* ws = (char*)d_ws;
  const size_t MB = 1ull << 20;
  u16* wqt = (u16*)(ws + 0 * MB);    // [2048][256] bf16
  u16* wkt = (u16*)(ws + 1 * MB);
  u16* wvt = (u16*)(ws + 2 * MB);
  u16* wot = (u16*)(ws + 3 * MB);    // [256][2048] bf16
  u16* qn  = (u16*)(ws + 4 * MB);    // [8192][256] bf16
  u16* kn  = (u16*)(ws + 8 * MB);
  u16* vn  = (u16*)(ws + 12 * MB);
  u16* qws = (u16*)(ws + 16 * MB);   // [32][2048][256] bf16 (q, pre-scaled log2e/16)
  u16* kws = (u16*)(ws + 48 * MB);   // [32][2048][256] bf16
  u16* attn = (u16*)(ws + 80 * MB);  // [8192][2048] bf16 (attention output)
  u16* vtw = (u16*)(ws + 112 * MB);  // [32][256][2048] bf16 (V^T, written by proj)

  transpose_conv<<<dim3(512, 4), 256, 0, stream>>>(Wq, Wk, Wv, Wo, wqt, wkt, wvt, wot);
  ln3_kernel<<<dim3(2048, 3), 256, 0, stream>>>(inq, key, val, gq, bqln, gk, bkln, gv, bvln,
                                                qn, kn, vn);
  proj_gemm<<<dim3(64, 16, 3), 256, 0, stream>>>(qn, kn, vn, wqt, wkt, wvt, bq, bk, bv,
                                                 qws, kws, vtw);
  flash_attn<<<256, 256, 0, stream>>>(qws, kws, vtw, attn);
  out_gemm<<<dim3(64, 4), 256, 0, stream>>>(attn, wot, bo, inq, (float*)d_out);
}

// Round 7
// 334.609 us; speedup vs baseline: 3.7461x; 3.7461x over previous
//
#include <hip/hip_runtime.h>

// Shapes: B=4, S=2048, D=256, H=8, KD=256; N=B*S=8192; H*KD=2048.
using bf16x8 = __attribute__((ext_vector_type(8))) __bf16;
using f32x4  = __attribute__((ext_vector_type(4))) float;
using f32x16 = __attribute__((ext_vector_type(16))) float;
typedef unsigned short u16;
typedef const __attribute__((address_space(1))) void* gas_p;
typedef __attribute__((address_space(3))) void* las_p;

#define LOG2E 1.4426950408889634f

__device__ __forceinline__ u16 f2bf(float f) {
  union { float f; unsigned u; } v; v.f = f;
  unsigned r = v.u + 0x7fffu + ((v.u >> 16) & 1u);
  return (u16)(r >> 16);
}

__device__ __forceinline__ unsigned pkbf(float a, float b) {
  unsigned r;
  asm("v_cvt_pk_bf16_f32 %0, %1, %2" : "=v"(r) : "v"(a), "v"(b));
  return r;
}

// 2^x via the native transcendental unit (one v_exp_f32).
__device__ __forceinline__ float exp2v(float x) {
  float r;
  asm("v_exp_f32 %0, %1" : "=v"(r) : "v"(x));
  return r;
}

__device__ __forceinline__ void gload16(const void* g, void* l) {
  __builtin_amdgcn_global_load_lds((gas_p)g, (las_p)l, 16, 0, 0);
}

#define MFMA(a, b, c)   __builtin_amdgcn_mfma_f32_16x16x32_bf16((a), (b), (c), 0, 0, 0)
#define MFMA32(a, b, c) __builtin_amdgcn_mfma_f32_32x32x16_bf16((a), (b), (c), 0, 0, 0)

// ---------------------------------------------------------------------------
// Kernel 1: transpose + f32->bf16 convert for the 4 weight matrices.
__global__ __launch_bounds__(256) void transpose_conv(
    const float* __restrict__ Wq, const float* __restrict__ Wk,
    const float* __restrict__ Wv, const float* __restrict__ Wo,
    u16* __restrict__ wqt, u16* __restrict__ wkt,
    u16* __restrict__ wvt, u16* __restrict__ wot)
{
  int z = blockIdx.y;
  const float* src = (z == 0) ? Wq : (z == 1) ? Wk : (z == 2) ? Wv : Wo;
  u16* dst = (z == 0) ? wqt : (z == 1) ? wkt : (z == 2) ? wvt : wot;
  int C = (z < 3) ? 2048 : 256;   // src cols
  int R = (z < 3) ? 256 : 2048;   // src rows
  int TC = C >> 5;
  int tc = blockIdx.x % TC, tr = blockIdx.x / TC;
  __shared__ float tile[32][33];
  int j = threadIdx.x & 31, i0 = threadIdx.x >> 5;
#pragma unroll
  for (int p = 0; p < 4; p++)
    tile[i0 + p * 8][j] = src[(tr * 32 + i0 + p * 8) * C + tc * 32 + j];
  __syncthreads();
#pragma unroll
  for (int p = 0; p < 4; p++)
    dst[(tc * 32 + i0 + p * 8) * R + tr * 32 + j] = f2bf(tile[j][i0 + p * 8]);
}

// ---------------------------------------------------------------------------
// Kernel 2: LayerNorm for the 3 input streams, f32 -> bf16. One wave per row.
__global__ __launch_bounds__(256) void ln3_kernel(
    const float* __restrict__ xq, const float* __restrict__ xk, const float* __restrict__ xv,
    const float* __restrict__ gq, const float* __restrict__ bq,
    const float* __restrict__ gk, const float* __restrict__ bk,
    const float* __restrict__ gv, const float* __restrict__ bv,
    u16* __restrict__ oq, u16* __restrict__ ok, u16* __restrict__ ov)
{
  int z = blockIdx.y;
  const float* x = (z == 0) ? xq : (z == 1) ? xk : xv;
  const float* g = (z == 0) ? gq : (z == 1) ? gk : gv;
  const float* be = (z == 0) ? bq : (z == 1) ? bk : bv;
  u16* o = (z == 0) ? oq : (z == 1) ? ok : ov;
  int w = threadIdx.x >> 6, l = threadIdx.x & 63;
  int row = blockIdx.x * 4 + w;
  float4 x4 = *(const float4*)(x + row * 256 + l * 4);
  float s = x4.x + x4.y + x4.z + x4.w;
  float sq = x4.x * x4.x + x4.y * x4.y + x4.z * x4.z + x4.w * x4.w;
#pragma unroll
  for (int mm = 1; mm < 64; mm <<= 1) { s += __shfl_xor(s, mm); sq += __shfl_xor(sq, mm); }
  float mu = s * (1.f / 256.f);
  float var = sq * (1.f / 256.f) - mu * mu;
  float rs = rsqrtf(var + 1e-5f);
  float4 g4 = *(const float4*)(g + l * 4);
  float4 b4 = *(const float4*)(be + l * 4);
  ushort4 o4;
  o4.x = f2bf((x4.x - mu) * rs * g4.x + b4.x);
  o4.y = f2bf((x4.y - mu) * rs * g4.y + b4.y);
  o4.z = f2bf((x4.z - mu) * rs * g4.z + b4.z);
  o4.w = f2bf((x4.w - mu) * rs * g4.w + b4.w);
  *(ushort4*)(o + row * 256 + l * 4) = o4;
}

// ---------------------------------------------------------------------------
// Kernel 3: projection GEMM. C[8192][2048] = A[8192][256] * W[256][2048] (+bias)
// z==2 (V stream) writes V^T [32 bh][256 kd][2048 s] directly (fused transpose).
// q stream pre-scaled by (1/16)*log2(e) so attention softmax runs in exp2 domain.
__global__ __launch_bounds__(256) void proj_gemm(
    const u16* __restrict__ qn, const u16* __restrict__ kn, const u16* __restrict__ vn,
    const u16* __restrict__ wqt, const u16* __restrict__ wkt, const u16* __restrict__ wvt,
    const float* __restrict__ bq, const float* __restrict__ bk, const float* __restrict__ bv,
    u16* __restrict__ qo, u16* __restrict__ ko, u16* __restrict__ vo)
{
  __shared__ u16 As[128 * 64];
  __shared__ u16 Bs[128 * 64];
  int z = blockIdx.z;
  const u16* A  = (z == 0) ? qn : (z == 1) ? kn : vn;
  const u16* Bt = (z == 0) ? wqt : (z == 1) ? wkt : wvt;
  const float* bias = (z == 0) ? bq : (z == 1) ? bk : bv;
  u16* Co = (z == 0) ? qo : (z == 1) ? ko : vo;
  float scale = (z == 0) ? 0.0625f * LOG2E : 1.0f;

  int i0 = blockIdx.x * 128, n0 = blockIdx.y * 128;
  int tid = threadIdx.x, w = tid >> 6, l = tid & 63;
  int wr = w >> 1, wc = w & 1, l15 = l & 15, qv = l >> 4;

  f32x4 acc[4][4] = {};

  for (int k0 = 0; k0 < 256; k0 += 64) {
    __syncthreads();
#pragma unroll
    for (int j = 0; j < 4; j++) {
      int c = (w * 4 + j) * 64 + l;
      int row = c >> 3, co = (c & 7) * 8;
      gload16(A + (i0 + row) * 256 + k0 + co, (char*)As + (w * 4 + j) * 1024);
      gload16(Bt + (n0 + row) * 256 + k0 + co, (char*)Bs + (w * 4 + j) * 1024);
    }
    __syncthreads();
#pragma unroll
    for (int kk = 0; kk < 2; kk++) {
      bf16x8 a[4], bfr[4];
#pragma unroll
      for (int m = 0; m < 4; m++)
        a[m] = *(const bf16x8*)(As + (wr * 64 + m * 16 + l15) * 64 + kk * 32 + qv * 8);
#pragma unroll
      for (int n = 0; n < 4; n++)
        bfr[n] = *(const bf16x8*)(Bs + (wc * 64 + n * 16 + l15) * 64 + kk * 32 + qv * 8);
#pragma unroll
      for (int m = 0; m < 4; m++)
#pragma unroll
        for (int n = 0; n < 4; n++) acc[m][n] = MFMA(a[m], bfr[n], acc[m][n]);
    }
  }

  if (z == 2) {
    // V^T epilogue: vt[(bb*8+h)*256 + kd][ss..ss+3], 8B packed stores.
#pragma unroll
    for (int n = 0; n < 4; n++) {
      int col = n0 + wc * 64 + n * 16 + l15;
      float bc = bias[col];
      int h = col >> 8, kd = col & 255;
#pragma unroll
      for (int m = 0; m < 4; m++) {
        int row0 = i0 + wr * 64 + m * 16 + qv * 4;
        int bb = row0 >> 11, ss = row0 & 2047;
        ushort4 o4;
        o4.x = f2bf(acc[m][n][0] + bc);
        o4.y = f2bf(acc[m][n][1] + bc);
        o4.z = f2bf(acc[m][n][2] + bc);
        o4.w = f2bf(acc[m][n][3] + bc);
        *(ushort4*)(Co + ((size_t)(bb * 8 + h) * 256 + kd) * 2048 + ss) = o4;
      }
    }
  } else {
#pragma unroll
    for (int n = 0; n < 4; n++) {
      int col = n0 + wc * 64 + n * 16 + l15;
      float bc = bias[col];
      int h = col >> 8, kd = col & 255;
#pragma unroll
      for (int m = 0; m < 4; m++) {
#pragma unroll
        for (int r = 0; r < 4; r++) {
          int row = i0 + wr * 64 + m * 16 + qv * 4 + r;
          int bb = row >> 11, ss = row & 2047;
          Co[((bb * 8 + h) * 2048 + ss) * 256 + kd] = f2bf((acc[m][n][r] + bc) * scale);
        }
      }
    }
  }
}

// ---------------------------------------------------------------------------
// Kernel 5: flash attention, 32x32x16 MFMA, swapped operands (round-3 base:
// 8 waves x 32 q, KVBLK=64, double-buffered 2x64KB, 128 VGPR) + intra-tile
// 2-half software pipeline: QK(sh0); QK(sh1); SM(sh0); PV(sh0); SM(sh1);
// PV(sh1) — SM VALU overlaps the adjacent independent MFMA cluster, while
// defer-max keeps the oacc-touching rescale rare. Softmax in exp2 domain.
__global__ __launch_bounds__(512, 2) void flash_attn(
    const u16* __restrict__ q, const u16* __restrict__ k,
    const u16* __restrict__ vt, u16* __restrict__ o)
{
  __shared__ char lds[131072];
  int f = blockIdx.x;
  int qt = f >> 5;
  int bh = (f & 7) | (((f >> 3) & 3) << 3);
  int b = bh >> 3, hh = bh & 7;
  int tid = threadIdx.x, w = tid >> 6, l = tid & 63;
  int l31 = l & 31, h = l >> 5;

  const u16* Q = q + (size_t)(bh * 2048 + qt * 256 + w * 32) * 256;
  const u16* K = k + (size_t)bh * 2048 * 256;
  const u16* V = vt + (size_t)bh * 256 * 2048;   // V^T [256][2048]

  // Q B-fragments: lane holds q-row = l31, d-slice = dt*16 + h*8 .. +8.
  bf16x8 qf[16];
#pragma unroll
  for (int dt = 0; dt < 16; dt++)
    qf[dt] = *(const bf16x8*)(Q + l31 * 256 + dt * 16 + h * 8);

  f32x16 oacc[8] = {};
  float m_ = -1e30f, lsum = 0.f;

  // Stage K/V tile t into base (swizzled; 8 waves x 8 gload16 = 64 KiB).
  auto stage = [&](int t, char* base) {
#pragma unroll
    for (int j = 0; j < 4; j++) {
      int c = w * 4 + j;
      int off = c * 1024 + l * 16;
      {
        int r = off >> 9, ps = l & 31;                 // K: row r, phys slot ps
        gload16(K + (size_t)(t * 64 + r) * 256 + ((ps ^ (r & 31)) << 3), base + off);
      }
      {
        int r = off >> 8, ps = l & 15;                 // V: 256B row r
        int lsl = ps ^ (r & 15);
        int d = r * 2 + (lsl >> 3);
        gload16(V + (size_t)d * 2048 + t * 64 + ((lsl & 7) << 3), base + 32768 + off);
      }
    }
  };

  // Online softmax for one 32-s half (lane-local q = l31; rows split by h).
  auto softmax_half = [&](f32x16& p, unsigned* pw) {
    float n0 = fmaxf(fmaxf(p[0], p[1]), fmaxf(p[2], p[3]));
    float n1 = fmaxf(fmaxf(p[4], p[5]), fmaxf(p[6], p[7]));
    float n2 = fmaxf(fmaxf(p[8], p[9]), fmaxf(p[10], p[11]));
    float n3 = fmaxf(fmaxf(p[12], p[13]), fmaxf(p[14], p[15]));
    float mt = fmaxf(fmaxf(n0, n1), fmaxf(n2, n3));
    mt = fmaxf(mt, __shfl_xor(mt, 32));
    if (__any(mt > m_ + 8.0f * LOG2E)) {         // defer-max (T13)
      float mn = fmaxf(m_, mt);
      float fsc = exp2v(m_ - mn);
      lsum *= fsc;
#pragma unroll
      for (int dt = 0; dt < 8; dt++)
#pragma unroll
        for (int i = 0; i < 16; i++) oacc[dt][i] *= fsc;
      m_ = mn;
    }
#pragma unroll
    for (int i = 0; i < 16; i++) { p[i] = exp2v(p[i] - m_); lsum += p[i]; }
#pragma unroll
    for (int i = 0; i < 8; i++) pw[i] = pkbf(p[2 * i], p[2 * i + 1]);
  };

  // PV for one half: kt_global in {2*hf, 2*hf+1}, P from pw[0..7].
  auto pv_half = [&](const unsigned* pw, int hf, const char* cur) {
#pragma unroll
    for (int ktl = 0; ktl < 2; ktl++) {
      int kt = hf * 2 + ktl;
      unsigned x0 = __shfl_xor(pw[4 * ktl + 0], 32);
      unsigned x1 = __shfl_xor(pw[4 * ktl + 1], 32);
      unsigned x2 = __shfl_xor(pw[4 * ktl + 2], 32);
      unsigned x3 = __shfl_xor(pw[4 * ktl + 3], 32);
      union { unsigned u[4]; bf16x8 v; } pa;
      pa.u[0] = h ? x2 : pw[4 * ktl + 0];
      pa.u[1] = h ? x3 : pw[4 * ktl + 1];
      pa.u[2] = h ? pw[4 * ktl + 2] : x0;
      pa.u[3] = h ? pw[4 * ktl + 3] : x1;
      __builtin_amdgcn_s_setprio(1);
#pragma unroll
      for (int dt = 0; dt < 8; dt++) {
        int d = dt * 32 + l31;
        int r = d >> 1;
        int lsl = (d & 1) * 8 + kt * 2 + h;
        bf16x8 vf = *(const bf16x8*)(cur + 32768 + r * 256 + ((lsl ^ (r & 15)) << 4));
        oacc[dt] = MFMA32(vf, pa.v, oacc[dt]);
      }
      __builtin_amdgcn_s_setprio(0);
    }
  };

  stage(0, lds);
  __syncthreads();

  for (int t = 0; t < 32; t++) {
    char* cur = lds + (size_t)(t & 1) * 65536;
    char* nxt = lds + (size_t)((t + 1) & 1) * 65536;
    if (t + 1 < 32) stage(t + 1, nxt);   // async DMA into other buffer

    // ---- QK^T both halves up front (independent MFMA chains).
    f32x16 p0 = {}, p1 = {};
    unsigned pw0[8], pw1[8];
    __builtin_amdgcn_s_setprio(1);
#pragma unroll
    for (int dt = 0; dt < 16; dt++) {
      int sl = ((dt * 2 + h) ^ l31) << 4;
      bf16x8 kf0 = *(const bf16x8*)(cur + l31 * 512 + sl);
      p0 = MFMA32(kf0, qf[dt], p0);
    }
#pragma unroll
    for (int dt = 0; dt < 16; dt++) {
      int sl = ((dt * 2 + h) ^ l31) << 4;
      bf16x8 kf1 = *(const bf16x8*)(cur + (32 + l31) * 512 + sl);
      p1 = MFMA32(kf1, qf[dt], p1);
    }
    __builtin_amdgcn_s_setprio(0);

    // ---- skewed pipeline: SM0 overlaps tail of QK1; SM1 overlaps PV0.
    softmax_half(p0, pw0);
    pv_half(pw0, 0, cur);
    softmax_half(p1, pw1);
    pv_half(pw1, 1, cur);

    asm volatile("s_waitcnt vmcnt(0)" ::: "memory");
    __syncthreads();
  }

  // ---- epilogue: normalize (lane-local q), transpose via LDS, store 16B.
  __syncthreads();
  float inv = 1.0f / (lsum + __shfl_xor(lsum, 32));
  char* wbase = (char*)lds + w * 8192;   // 16 q-rows x 512B per warp region
  int qr15 = l31 & 15;
#pragma unroll
  for (int ph = 0; ph < 2; ph++) {
    if ((l31 >> 4) == ph) {
#pragma unroll
      for (int dt = 0; dt < 8; dt++) {
#pragma unroll
        for (int rg = 0; rg < 4; rg++) {
          uint2 uu;
          uu.x = pkbf(oacc[dt][rg * 4 + 0] * inv, oacc[dt][rg * 4 + 1] * inv);
          uu.y = pkbf(oacc[dt][rg * 4 + 2] * inv, oacc[dt][rg * 4 + 3] * inv);
          *(uint2*)(wbase + qr15 * 512 + ((dt * 64 + rg * 16) ^ (qr15 << 4)) + h * 8) = uu;
        }
      }
    }
    asm volatile("s_waitcnt lgkmcnt(0)" ::: "memory");
    __builtin_amdgcn_sched_barrier(0);
#pragma unroll
    for (int c = 0; c < 8; c++) {
      int qr = c * 2 + h;
      uint4 vv = *(const uint4*)(wbase + qr * 512 + ((l31 ^ qr) << 4));
      int s = qt * 256 + w * 32 + ph * 16 + qr;
      *(uint4*)((char*)o + (size_t)(b * 2048 + s) * 4096 + hh * 512 + l31 * 16) = vv;
    }
    asm volatile("s_waitcnt lgkmcnt(0)" ::: "memory");
  }
}

// ---------------------------------------------------------------------------
// Kernel 6: output projection + bias + residual.
__global__ __launch_bounds__(256) void out_gemm(
    const u16* __restrict__ A, const u16* __restrict__ Bt,
    const float* __restrict__ bo, const float* __restrict__ resid,
    float* __restrict__ out)
{
  __shared__ u16 As[128 * 64];
  __shared__ u16 Bs[64 * 64];
  int i0 = blockIdx.x * 128, n0 = blockIdx.y * 64;
  int tid = threadIdx.x, w = tid >> 6, l = tid & 63, l15 = l & 15, qv = l >> 4;

  f32x4 acc[2][4] = {};

  for (int k0 = 0; k0 < 2048; k0 += 64) {
    __syncthreads();
#pragma unroll
    for (int j = 0; j < 4; j++) {
      int c = (w * 4 + j) * 64 + l;
      int row = c >> 3, co = (c & 7) * 8;
      gload16(A + (i0 + row) * 2048 + k0 + co, (char*)As + (w * 4 + j) * 1024);
    }
#pragma unroll
    for (int j = 0; j < 2; j++) {
      int c = (w * 2 + j) * 64 + l;
      int row = c >> 3, co = (c & 7) * 8;
      gload16(Bt + (n0 + row) * 2048 + k0 + co, (char*)Bs + (w * 2 + j) * 1024);
    }
    __syncthreads();
#pragma unroll
    for (int kk = 0; kk < 2; kk++) {
      bf16x8 a[2], bfr[4];
#pragma unroll
      for (int m = 0; m < 2; m++)
        a[m] = *(const bf16x8*)(As + (w * 32 + m * 16 + l15) * 64 + kk * 32 + qv * 8);
#pragma unroll
      for (int n = 0; n < 4; n++)
        bfr[n] = *(const bf16x8*)(Bs + (n * 16 + l15) * 64 + kk * 32 + qv * 8);
#pragma unroll
      for (int m = 0; m < 2; m++)
#pragma unroll
        for (int n = 0; n < 4; n++) acc[m][n] = MFMA(a[m], bfr[n], acc[m][n]);
    }
  }

#pragma unroll
  for (int n = 0; n < 4; n++) {
    int col = n0 + n * 16 + l15;
    float bc = bo[col];
#pragma unroll
    for (int m = 0; m < 2; m++)
#pragma unroll
      for (int r = 0; r < 4; r++) {
        int row = i0 + w * 32 + m * 16 + qv * 4 + r;
        out[row * 256 + col] = acc[m][n][r] + bc + resid[row * 256 + col];
      }
  }
}

// ---------------------------------------------------------------------------
extern "C" void kernel_launch(void* const* d_in, const int* in_sizes, int n_in,
                              void* d_out, int out_size, void* d_ws, size_t ws_size,
                              hipStream_t stream)
{
  const float* inq  = (const float*)d_in[0];
  const float* key  = (const float*)d_in[1];
  const float* val  = (const float*)d_in[2];
  const float* gq   = (const float*)d_in[3];
  const float* bqln = (const float*)d_in[4];
  const float* gk   = (const float*)d_in[5];
  const float* bkln = (const float*)d_in[6];
  const float* gv   = (const float*)d_in[7];
  const float* bvln = (const float*)d_in[8];
  const float* Wq   = (const float*)d_in[9];
  const float* bq   = (const float*)d_in[10];
  const float* Wk   = (const float*)d_in[11];
  const float* bk   = (const float*)d_in[12];
  const float* Wv   = (const float*)d_in[13];
  const float* bv   = (const float*)d_in[14];
  const float* Wo   = (const float*)d_in[15];
  const float* bo   = (const float*)d_in[16];

  char* ws = (char*)d_ws;
  const size_t MB = 1ull << 20;
  u16* wqt = (u16*)(ws + 0 * MB);    // [2048][256] bf16
  u16* wkt = (u16*)(ws + 1 * MB);
  u16* wvt = (u16*)(ws + 2 * MB);
  u16* wot = (u16*)(ws + 3 * MB);    // [256][2048] bf16
  u16* qn  = (u16*)(ws + 4 * MB);    // [8192][256] bf16
  u16* kn  = (u16*)(ws + 8 * MB);
  u16* vn  = (u16*)(ws + 12 * MB);
  u16* qws = (u16*)(ws + 16 * MB);   // [32][2048][256] bf16 (q, pre-scaled log2e/16)
  u16* kws = (u16*)(ws + 48 * MB);   // [32][2048][256] bf16
  u16* attn = (u16*)(ws + 80 * MB);  // [8192][2048] bf16 (attention output)
  u16* vtw = (u16*)(ws + 112 * MB);  // [32][256][2048] bf16 (V^T, written by proj)

  transpose_conv<<<dim3(512, 4), 256, 0, stream>>>(Wq, Wk, Wv, Wo, wqt, wkt, wvt, wot);
  ln3_kernel<<<dim3(2048, 3), 256, 0, stream>>>(inq, key, val, gq, bqln, gk, bkln, gv, bvln,
                                                qn, kn, vn);
  proj_gemm<<<dim3(64, 16, 3), 256, 0, stream>>>(qn, kn, vn, wqt, wkt, wvt, bq, bk, bv,
                                                 qws, kws, vtw);
  flash_attn<<<256, 512, 0, stream>>>(qws, kws, vtw, attn);
  out_gemm<<<dim3(64, 4), 256, 0, stream>>>(attn, wot, bo, inq, (float*)d_out);
}

// Round 8
// 251.493 us; speedup vs baseline: 4.9841x; 1.3305x over previous
//
#include <hip/hip_runtime.h>

// Shapes: B=4, S=2048, D=256, H=8, KD=256; N=B*S=8192; H*KD=2048.
using bf16x8 = __attribute__((ext_vector_type(8))) __bf16;
using f32x4  = __attribute__((ext_vector_type(4))) float;
using f32x16 = __attribute__((ext_vector_type(16))) float;
using uint2v = __attribute__((ext_vector_type(2))) unsigned;
typedef unsigned short u16;
typedef const __attribute__((address_space(1))) void* gas_p;
typedef __attribute__((address_space(3))) void* las_p;

#define LOG2E 1.4426950408889634f

__device__ __forceinline__ u16 f2bf(float f) {
  union { float f; unsigned u; } v; v.f = f;
  unsigned r = v.u + 0x7fffu + ((v.u >> 16) & 1u);
  return (u16)(r >> 16);
}

__device__ __forceinline__ unsigned pkbf(float a, float b) {
  unsigned r;
  asm("v_cvt_pk_bf16_f32 %0, %1, %2" : "=v"(r) : "v"(a), "v"(b));
  return r;
}

// 2^x via the native transcendental unit (one v_exp_f32).
__device__ __forceinline__ float exp2v(float x) {
  float r;
  asm("v_exp_f32 %0, %1" : "=v"(r) : "v"(x));
  return r;
}

// 4 floats -> 4 fp8 e4m3 packed in one dword (bytes ascending).
__device__ __forceinline__ unsigned pk_fp8x4(float a, float b, float c, float d) {
  int w = __builtin_amdgcn_cvt_pk_fp8_f32(a, b, 0, false);
  w = __builtin_amdgcn_cvt_pk_fp8_f32(c, d, w, true);
  return (unsigned)w;
}

// Cross-half exchange: x = {lo: own a, hi: partner b}, y = {lo: partner a, hi: own b}.
__device__ __forceinline__ uint2v swap32(unsigned a, unsigned b) {
  return __builtin_amdgcn_permlane32_swap(a, b, false, false);
}

__device__ __forceinline__ void gload16(const void* g, void* l) {
  __builtin_amdgcn_global_load_lds((gas_p)g, (las_p)l, 16, 0, 0);
}

#define MFMA(a, b, c)   __builtin_amdgcn_mfma_f32_16x16x32_bf16((a), (b), (c), 0, 0, 0)
#define MFMA32(a, b, c) __builtin_amdgcn_mfma_f32_32x32x16_bf16((a), (b), (c), 0, 0, 0)
#define MFMA8(a, b, c)  __builtin_amdgcn_mfma_f32_32x32x16_fp8_fp8((a), (b), (c), 0, 0, 0)

// ---------------------------------------------------------------------------
// Kernel 1: transpose + f32->bf16 convert for the 4 weight matrices.
__global__ __launch_bounds__(256) void transpose_conv(
    const float* __restrict__ Wq, const float* __restrict__ Wk,
    const float* __restrict__ Wv, const float* __restrict__ Wo,
    u16* __restrict__ wqt, u16* __restrict__ wkt,
    u16* __restrict__ wvt, u16* __restrict__ wot)
{
  int z = blockIdx.y;
  const float* src = (z == 0) ? Wq : (z == 1) ? Wk : (z == 2) ? Wv : Wo;
  u16* dst = (z == 0) ? wqt : (z == 1) ? wkt : (z == 2) ? wvt : wot;
  int C = (z < 3) ? 2048 : 256;   // src cols
  int R = (z < 3) ? 256 : 2048;   // src rows
  int TC = C >> 5;
  int tc = blockIdx.x % TC, tr = blockIdx.x / TC;
  __shared__ float tile[32][33];
  int j = threadIdx.x & 31, i0 = threadIdx.x >> 5;
#pragma unroll
  for (int p = 0; p < 4; p++)
    tile[i0 + p * 8][j] = src[(tr * 32 + i0 + p * 8) * C + tc * 32 + j];
  __syncthreads();
#pragma unroll
  for (int p = 0; p < 4; p++)
    dst[(tc * 32 + i0 + p * 8) * R + tr * 32 + j] = f2bf(tile[j][i0 + p * 8]);
}

// ---------------------------------------------------------------------------
// Kernel 2: LayerNorm for the 3 input streams, f32 -> bf16. One wave per row.
__global__ __launch_bounds__(256) void ln3_kernel(
    const float* __restrict__ xq, const float* __restrict__ xk, const float* __restrict__ xv,
    const float* __restrict__ gq, const float* __restrict__ bq,
    const float* __restrict__ gk, const float* __restrict__ bk,
    const float* __restrict__ gv, const float* __restrict__ bv,
    u16* __restrict__ oq, u16* __restrict__ ok, u16* __restrict__ ov)
{
  int z = blockIdx.y;
  const float* x = (z == 0) ? xq : (z == 1) ? xk : xv;
  const float* g = (z == 0) ? gq : (z == 1) ? gk : gv;
  const float* be = (z == 0) ? bq : (z == 1) ? bk : bv;
  u16* o = (z == 0) ? oq : (z == 1) ? ok : ov;
  int w = threadIdx.x >> 6, l = threadIdx.x & 63;
  int row = blockIdx.x * 4 + w;
  float4 x4 = *(const float4*)(x + row * 256 + l * 4);
  float s = x4.x + x4.y + x4.z + x4.w;
  float sq = x4.x * x4.x + x4.y * x4.y + x4.z * x4.z + x4.w * x4.w;
#pragma unroll
  for (int mm = 1; mm < 64; mm <<= 1) { s += __shfl_xor(s, mm); sq += __shfl_xor(sq, mm); }
  float mu = s * (1.f / 256.f);
  float var = sq * (1.f / 256.f) - mu * mu;
  float rs = rsqrtf(var + 1e-5f);
  float4 g4 = *(const float4*)(g + l * 4);
  float4 b4 = *(const float4*)(be + l * 4);
  ushort4 o4;
  o4.x = f2bf((x4.x - mu) * rs * g4.x + b4.x);
  o4.y = f2bf((x4.y - mu) * rs * g4.y + b4.y);
  o4.z = f2bf((x4.z - mu) * rs * g4.z + b4.z);
  o4.w = f2bf((x4.w - mu) * rs * g4.w + b4.w);
  *(ushort4*)(o + row * 256 + l * 4) = o4;
}

// ---------------------------------------------------------------------------
// Kernel 3: projection GEMM. C[8192][2048] = A[8192][256] * W[256][2048] (+bias)
// z==0/1: q/k -> [B,H,S,KD] bf16 (q pre-scaled by log2e/16 for exp2 softmax).
// z==2: V^T [32 bh][256 kd][2048 s] fp8 e4m3 with per-64-block s-permutation
//       perm(s) = ((s>>3)&3)*16 + ((s>>5)&1)*8 + (s&7) (pairs s and s+32 into
//       one 16B granule for the flash PV reads).
__global__ __launch_bounds__(256) void proj_gemm(
    const u16* __restrict__ qn, const u16* __restrict__ kn, const u16* __restrict__ vn,
    const u16* __restrict__ wqt, const u16* __restrict__ wkt, const u16* __restrict__ wvt,
    const float* __restrict__ bq, const float* __restrict__ bk, const float* __restrict__ bv,
    u16* __restrict__ qo, u16* __restrict__ ko, unsigned char* __restrict__ vo)
{
  __shared__ u16 As[128 * 64];
  __shared__ u16 Bs[128 * 64];
  int z = blockIdx.z;
  const u16* A  = (z == 0) ? qn : (z == 1) ? kn : vn;
  const u16* Bt = (z == 0) ? wqt : (z == 1) ? wkt : wvt;
  const float* bias = (z == 0) ? bq : (z == 1) ? bk : bv;
  float scale = (z == 0) ? 0.0625f * LOG2E : 1.0f;

  int i0 = blockIdx.x * 128, n0 = blockIdx.y * 128;
  int tid = threadIdx.x, w = tid >> 6, l = tid & 63;
  int wr = w >> 1, wc = w & 1, l15 = l & 15, qv = l >> 4;

  f32x4 acc[4][4] = {};

  for (int k0 = 0; k0 < 256; k0 += 64) {
    __syncthreads();
#pragma unroll
    for (int j = 0; j < 4; j++) {
      int c = (w * 4 + j) * 64 + l;
      int row = c >> 3, co = (c & 7) * 8;
      gload16(A + (i0 + row) * 256 + k0 + co, (char*)As + (w * 4 + j) * 1024);
      gload16(Bt + (n0 + row) * 256 + k0 + co, (char*)Bs + (w * 4 + j) * 1024);
    }
    __syncthreads();
#pragma unroll
    for (int kk = 0; kk < 2; kk++) {
      bf16x8 a[4], bfr[4];
#pragma unroll
      for (int m = 0; m < 4; m++)
        a[m] = *(const bf16x8*)(As + (wr * 64 + m * 16 + l15) * 64 + kk * 32 + qv * 8);
#pragma unroll
      for (int n = 0; n < 4; n++)
        bfr[n] = *(const bf16x8*)(Bs + (wc * 64 + n * 16 + l15) * 64 + kk * 32 + qv * 8);
#pragma unroll
      for (int m = 0; m < 4; m++)
#pragma unroll
        for (int n = 0; n < 4; n++) acc[m][n] = MFMA(a[m], bfr[n], acc[m][n]);
    }
  }

  if (z == 2) {
    // V^T fp8 epilogue with permuted s layout (4 consecutive s per store).
#pragma unroll
    for (int n = 0; n < 4; n++) {
      int col = n0 + wc * 64 + n * 16 + l15;
      float bc = bias[col];
      int hd = col >> 8, kd = col & 255;
#pragma unroll
      for (int m = 0; m < 4; m++) {
        int row0 = i0 + wr * 64 + m * 16 + qv * 4;
        int bb = row0 >> 11, ss = row0 & 2047;
        unsigned wv = pk_fp8x4(acc[m][n][0] + bc, acc[m][n][1] + bc,
                               acc[m][n][2] + bc, acc[m][n][3] + bc);
        int pos = (ss & ~63) | (((ss >> 3) & 3) << 4) | (((ss >> 5) & 1) << 3) | (ss & 7);
        *(unsigned*)(vo + ((size_t)(bb * 8 + hd) * 256 + kd) * 2048 + pos) = wv;
      }
    }
  } else {
    u16* Co = (z == 0) ? qo : ko;
#pragma unroll
    for (int n = 0; n < 4; n++) {
      int col = n0 + wc * 64 + n * 16 + l15;
      float bc = bias[col];
      int hd = col >> 8, kd = col & 255;
#pragma unroll
      for (int m = 0; m < 4; m++) {
#pragma unroll
        for (int r = 0; r < 4; r++) {
          int row = i0 + wr * 64 + m * 16 + qv * 4 + r;
          int bb = row >> 11, ss = row & 2047;
          Co[((bb * 8 + hd) * 2048 + ss) * 256 + kd] = f2bf((acc[m][n][r] + bc) * scale);
        }
      }
    }
  }
}

// ---------------------------------------------------------------------------
// Kernel 5: flash attention (round-3 structure: 8 waves x 32 q, KVBLK=64,
// double-buffered, interleaved dual QK chains) with:
//  - PV in fp8: V^T tile 16 KB (pair-packed: one b128 = frags for kt and kt+2),
//    P packed to fp8 via cvt_pk_fp8, frags built with ONE permlane32_swap each.
//  - exp2-domain softmax (Q pre-scaled log2e/16), defer-max THR=7 (log2) so
//    P <= 128 < fp8 e4m3 max 448.
// LDS: 2 x (32 KB K + 16 KB V) = 96 KB. Grid 256 flat, XCD swizzle.
__global__ __launch_bounds__(512, 2) void flash_attn(
    const u16* __restrict__ q, const u16* __restrict__ k,
    const unsigned char* __restrict__ vt, u16* __restrict__ o)
{
  __shared__ char lds[98304];
  int f = blockIdx.x;
  int qt = f >> 5;
  int bh = (f & 7) | (((f >> 3) & 3) << 3);
  int b = bh >> 3, hh = bh & 7;
  int tid = threadIdx.x, w = tid >> 6, l = tid & 63;
  int l31 = l & 31, h = l >> 5;

  const u16* Q = q + (size_t)(bh * 2048 + qt * 256 + w * 32) * 256;
  const u16* K = k + (size_t)bh * 2048 * 256;
  const unsigned char* V = vt + (size_t)bh * 256 * 2048;   // V^T fp8, s-permuted

  // Q B-fragments: lane holds q-row = l31, d-slice = dt*16 + h*8 .. +8.
  bf16x8 qf[16];
#pragma unroll
  for (int dt = 0; dt < 16; dt++)
    qf[dt] = *(const bf16x8*)(Q + l31 * 256 + dt * 16 + h * 8);

  f32x16 oacc[8] = {};
  float m_ = -1e30f, lsum = 0.f;

  // Stage K (32 KB, bf16, row^slot swizzle) + V (16 KB fp8, granule^(row&15)).
  auto stage = [&](int t, char* base) {
#pragma unroll
    for (int j = 0; j < 4; j++) {
      int c = w * 4 + j;
      int off = c * 1024 + l * 16;
      int r = off >> 9, ps = l & 31;
      gload16(K + (size_t)(t * 64 + r) * 256 + ((ps ^ (r & 31)) << 3), base + off);
    }
#pragma unroll
    for (int j = 0; j < 2; j++) {
      int c = w * 2 + j;
      int off = c * 1024 + l * 16;
      int r = off >> 8, pg = (off >> 4) & 15;
      int g = pg ^ (r & 15);
      int d = r + 64 * (g >> 2), sc = g & 3;
      gload16(V + (size_t)d * 2048 + t * 64 + sc * 16, base + 32768 + off);
    }
  };

  stage(0, lds);
  __syncthreads();

  for (int t = 0; t < 32; t++) {
    char* cur = lds + (size_t)(t & 1) * 49152;
    char* nxt = lds + (size_t)((t + 1) & 1) * 49152;
    if (t + 1 < 32) stage(t + 1, nxt);   // async DMA into other buffer

    // ---- QK^T: two interleaved MFMA chains (s-tiles [0,32) and [32,64)).
    f32x16 p0 = {}, p1 = {};
    __builtin_amdgcn_s_setprio(1);
#pragma unroll
    for (int dt = 0; dt < 16; dt++) {
      int sl = ((dt * 2 + h) ^ l31) << 4;
      bf16x8 kf0 = *(const bf16x8*)(cur + l31 * 512 + sl);
      bf16x8 kf1 = *(const bf16x8*)(cur + (32 + l31) * 512 + sl);
      p0 = MFMA32(kf0, qf[dt], p0);
      p1 = MFMA32(kf1, qf[dt], p1);
    }
    __builtin_amdgcn_s_setprio(0);

    // ---- online softmax (lane-local; q = l31 on both halves), exp2 domain.
    float n0 = fmaxf(fmaxf(p0[0], p0[1]), fmaxf(p0[2], p0[3]));
    float n1 = fmaxf(fmaxf(p0[4], p0[5]), fmaxf(p0[6], p0[7]));
    float n2 = fmaxf(fmaxf(p0[8], p0[9]), fmaxf(p0[10], p0[11]));
    float n3 = fmaxf(fmaxf(p0[12], p0[13]), fmaxf(p0[14], p0[15]));
    float n4 = fmaxf(fmaxf(p1[0], p1[1]), fmaxf(p1[2], p1[3]));
    float n5 = fmaxf(fmaxf(p1[4], p1[5]), fmaxf(p1[6], p1[7]));
    float n6 = fmaxf(fmaxf(p1[8], p1[9]), fmaxf(p1[10], p1[11]));
    float n7 = fmaxf(fmaxf(p1[12], p1[13]), fmaxf(p1[14], p1[15]));
    float mt = fmaxf(fmaxf(fmaxf(n0, n1), fmaxf(n2, n3)),
                     fmaxf(fmaxf(n4, n5), fmaxf(n6, n7)));
    {
      uint2v mr = swap32(__builtin_bit_cast(unsigned, mt), __builtin_bit_cast(unsigned, mt));
      mt = fmaxf(__builtin_bit_cast(float, mr.x), __builtin_bit_cast(float, mr.y));
    }
    if (__any(mt > m_ + 7.0f)) {               // defer-max; P bounded by 2^7
      float mn = fmaxf(m_, mt);
      float fsc = exp2v(m_ - mn);
      lsum *= fsc;
#pragma unroll
      for (int dt = 0; dt < 8; dt++)
#pragma unroll
        for (int i = 0; i < 16; i++) oacc[dt][i] *= fsc;
      m_ = mn;
    }
#pragma unroll
    for (int i = 0; i < 16; i++) { p0[i] = exp2v(p0[i] - m_); lsum += p0[i]; }
#pragma unroll
    for (int i = 0; i < 16; i++) { p1[i] = exp2v(p1[i] - m_); lsum += p1[i]; }

    // ---- pack P to fp8 words: word j = p[4j..4j+3] (s ascending per group).
    unsigned pwf0[4], pwf1[4];
#pragma unroll
    for (int j = 0; j < 4; j++) {
      pwf0[j] = pk_fp8x4(p0[4 * j], p0[4 * j + 1], p0[4 * j + 2], p0[4 * j + 3]);
      pwf1[j] = pk_fp8x4(p1[4 * j], p1[4 * j + 1], p1[4 * j + 2], p1[4 * j + 3]);
    }

    // ---- PV (fp8): one permlane32_swap per P-frag; one b128 V read feeds
    //      the kt and kt+2 MFMAs (pair-packed granules).
#pragma unroll
    for (int k2 = 0; k2 < 2; k2++) {
      uint2v f0 = swap32(pwf0[k2 * 2], pwf0[k2 * 2 + 1]);   // half 0: kt = k2
      uint2v f1 = swap32(pwf1[k2 * 2], pwf1[k2 * 2 + 1]);   // half 1: kt = k2+2
      long long pA = (long long)(((unsigned long long)f0.y << 32) | f0.x);
      long long pB = (long long)(((unsigned long long)f1.y << 32) | f1.x);
      __builtin_amdgcn_s_setprio(1);
#pragma unroll
      for (int dt = 0; dt < 8; dt++) {
        int r = (dt & 1) * 32 + l31;
        int g = (dt >> 1) * 4 + k2 * 2 + h;
        const uint4 vv = *(const uint4*)(cur + 32768 + r * 256 + ((g ^ (r & 15)) << 4));
        long long vA = (long long)(((unsigned long long)vv.y << 32) | vv.x);
        long long vB = (long long)(((unsigned long long)vv.w << 32) | vv.z);
        oacc[dt] = MFMA8(vA, pA, oacc[dt]);
        oacc[dt] = MFMA8(vB, pB, oacc[dt]);
      }
      __builtin_amdgcn_s_setprio(0);
    }

    asm volatile("s_waitcnt vmcnt(0)" ::: "memory");
    __syncthreads();
  }

  // ---- epilogue: normalize (lane-local q), transpose via LDS, store 16B.
  __syncthreads();
  float lsc;
  {
    uint2v lr = swap32(__builtin_bit_cast(unsigned, lsum), __builtin_bit_cast(unsigned, lsum));
    lsc = __builtin_bit_cast(float, lr.x) + __builtin_bit_cast(float, lr.y);
  }
  float inv = 1.0f / lsc;
  char* wbase = (char*)lds + w * 8192;   // 16 q-rows x 512B per warp region
  int qr15 = l31 & 15;
#pragma unroll
  for (int ph = 0; ph < 2; ph++) {
    if ((l31 >> 4) == ph) {
#pragma unroll
      for (int dt = 0; dt < 8; dt++) {
#pragma unroll
        for (int rg = 0; rg < 4; rg++) {
          uint2 uu;
          uu.x = pkbf(oacc[dt][rg * 4 + 0] * inv, oacc[dt][rg * 4 + 1] * inv);
          uu.y = pkbf(oacc[dt][rg * 4 + 2] * inv, oacc[dt][rg * 4 + 3] * inv);
          *(uint2*)(wbase + qr15 * 512 + ((dt * 64 + rg * 16) ^ (qr15 << 4)) + h * 8) = uu;
        }
      }
    }
    asm volatile("s_waitcnt lgkmcnt(0)" ::: "memory");
    __builtin_amdgcn_sched_barrier(0);
#pragma unroll
    for (int c = 0; c < 8; c++) {
      int qr = c * 2 + h;
      uint4 vv = *(const uint4*)(wbase + qr * 512 + ((l31 ^ qr) << 4));
      int s = qt * 256 + w * 32 + ph * 16 + qr;
      *(uint4*)((char*)o + (size_t)(b * 2048 + s) * 4096 + hh * 512 + l31 * 16) = vv;
    }
    asm volatile("s_waitcnt lgkmcnt(0)" ::: "memory");
  }
}

// ---------------------------------------------------------------------------
// Kernel 6: output projection + bias + residual.
__global__ __launch_bounds__(256) void out_gemm(
    const u16* __restrict__ A, const u16* __restrict__ Bt,
    const float* __restrict__ bo, const float* __restrict__ resid,
    float* __restrict__ out)
{
  __shared__ u16 As[128 * 64];
  __shared__ u16 Bs[64 * 64];
  int i0 = blockIdx.x * 128, n0 = blockIdx.y * 64;
  int tid = threadIdx.x, w = tid >> 6, l = tid & 63, l15 = l & 15, qv = l >> 4;

  f32x4 acc[2][4] = {};

  for (int k0 = 0; k0 < 2048; k0 += 64) {
    __syncthreads();
#pragma unroll
    for (int j = 0; j < 4; j++) {
      int c = (w * 4 + j) * 64 + l;
      int row = c >> 3, co = (c & 7) * 8;
      gload16(A + (i0 + row) * 2048 + k0 + co, (char*)As + (w * 4 + j) * 1024);
    }
#pragma unroll
    for (int j = 0; j < 2; j++) {
      int c = (w * 2 + j) * 64 + l;
      int row = c >> 3, co = (c & 7) * 8;
      gload16(Bt + (n0 + row) * 2048 + k0 + co, (char*)Bs + (w * 2 + j) * 1024);
    }
    __syncthreads();
#pragma unroll
    for (int kk = 0; kk < 2; kk++) {
      bf16x8 a[2], bfr[4];
#pragma unroll
      for (int m = 0; m < 2; m++)
        a[m] = *(const bf16x8*)(As + (w * 32 + m * 16 + l15) * 64 + kk * 32 + qv * 8);
#pragma unroll
      for (int n = 0; n < 4; n++)
        bfr[n] = *(const bf16x8*)(Bs + (n * 16 + l15) * 64 + kk * 32 + qv * 8);
#pragma unroll
      for (int m = 0; m < 2; m++)
#pragma unroll
        for (int n = 0; n < 4; n++) acc[m][n] = MFMA(a[m], bfr[n], acc[m][n]);
    }
  }

#pragma unroll
  for (int n = 0; n < 4; n++) {
    int col = n0 + n * 16 + l15;
    float bc = bo[col];
#pragma unroll
    for (int m = 0; m < 2; m++)
#pragma unroll
      for (int r = 0; r < 4; r++) {
        int row = i0 + w * 32 + m * 16 + qv * 4 + r;
        out[row * 256 + col] = acc[m][n][r] + bc + resid[row * 256 + col];
      }
  }
}

// ---------------------------------------------------------------------------
extern "C" void kernel_launch(void* const* d_in, const int* in_sizes, int n_in,
                              void* d_out, int out_size, void* d_ws, size_t ws_size,
                              hipStream_t stream)
{
  const float* inq  = (const float*)d_in[0];
  const float* key  = (const float*)d_in[1];
  const float* val  = (const float*)d_in[2];
  const float* gq   = (const float*)d_in[3];
  const float* bqln = (const float*)d_in[4];
  const float* gk   = (const float*)d_in[5];
  const float* bkln = (const float*)d_in[6];
  const float* gv   = (const float*)d_in[7];
  const float* bvln = (const float*)d_in[8];
  const float* Wq   = (const float*)d_in[9];
  const float* bq   = (const float*)d_in[10];
  const float* Wk   = (const float*)d_in[11];
  const float* bk   = (const float*)d_in[12];
  const float* Wv   = (const float*)d_in[13];
  const float* bv   = (const float*)d_in[14];
  const float* Wo   = (const float*)d_in[15];
  const float* bo   = (const float*)d_in[16];

  char* ws = (char*)d_ws;
  const size_t MB = 1ull << 20;
  u16* wqt = (u16*)(ws + 0 * MB);    // [2048][256] bf16
  u16* wkt = (u16*)(ws + 1 * MB);
  u16* wvt = (u16*)(ws + 2 * MB);
  u16* wot = (u16*)(ws + 3 * MB);    // [256][2048] bf16
  u16* qn  = (u16*)(ws + 4 * MB);    // [8192][256] bf16
  u16* kn  = (u16*)(ws + 8 * MB);
  u16* vn  = (u16*)(ws + 12 * MB);
  u16* qws = (u16*)(ws + 16 * MB);   // [32][2048][256] bf16 (q, pre-scaled log2e/16)
  u16* kws = (u16*)(ws + 48 * MB);   // [32][2048][256] bf16
  u16* attn = (u16*)(ws + 80 * MB);  // [8192][2048] bf16 (attention output)
  unsigned char* vtw = (unsigned char*)(ws + 112 * MB);  // [32][256][2048] fp8 V^T

  transpose_conv<<<dim3(512, 4), 256, 0, stream>>>(Wq, Wk, Wv, Wo, wqt, wkt, wvt, wot);
  ln3_kernel<<<dim3(2048, 3), 256, 0, stream>>>(inq, key, val, gq, bqln, gk, bkln, gv, bvln,
                                                qn, kn, vn);
  proj_gemm<<<dim3(64, 16, 3), 256, 0, stream>>>(qn, kn, vn, wqt, wkt, wvt, bq, bk, bv,
                                                 qws, kws, vtw);
  flash_attn<<<256, 512, 0, stream>>>(qws, kws, vtw, attn);
  out_gemm<<<dim3(64, 4), 256, 0, stream>>>(attn, wot, bo, inq, (float*)d_out);
}